// Round 10
// baseline (3338.193 us; speedup 1.0000x reference)
//
#include <hip/hip_runtime.h>
#include <cstdint>
#include <cstddef>

// Problem constants (match reference)
#define S_LEN 256
#define BB    32
#define EMBD  256
#define HID   256
#define NTAG  10
#define L_TOT (BB*S_LEN)      // 8192 flattened viterbi length
#define NEGV  -10000.0f
#define SOS_I 1
#define EOS_I 2

__device__ __forceinline__ float sigf(float x) { return 1.0f / (1.0f + expf(-x)); }

// ---------------------------------------------------------------------------
// prep_all: fused embedding gather + weight transpose + bias combine.
// blocks [0,8192): E rows; [8192,12288): Wt; 12288: bias.
// ---------------------------------------------------------------------------
__global__ __launch_bounds__(256) void prep_all(
    const int* __restrict__ x, const float* __restrict__ emb,
    const float* __restrict__ Wih_f, const float* __restrict__ Whh_f,
    const float* __restrict__ Wih_b, const float* __restrict__ Whh_b,
    const float* __restrict__ bih_f, const float* __restrict__ bhh_f,
    const float* __restrict__ bih_b, const float* __restrict__ bhh_b,
    float* __restrict__ E, float* __restrict__ Wt, float* __restrict__ bc) {
    const int blk = blockIdx.x;
    const int tid = threadIdx.x;
    if (blk < 8192) {                  // E[t*32+b][m] = emb[x[b][t]][m]
        const int t = blk >> 5, b = blk & 31;
        const int xi = x[b * S_LEN + t];
        E[(size_t)blk * EMBD + tid] = emb[(size_t)xi * EMBD + tid];
    } else if (blk < 8192 + 4096) {    // Wt[d][k][j] (k-major)
        const int idx = blk - 8192;
        const int dk = idx >> 2;       // d*512 + k
        const int d = dk >> 9, k = dk & 511;
        const int j = (idx & 3) * 256 + tid;
        const float* src = (d == 0) ? ((k < 256) ? Wih_f : Whh_f)
                                    : ((k < 256) ? Wih_b : Whh_b);
        Wt[(size_t)dk * 1024 + j] = src[(size_t)j * 256 + (k & 255)];
    } else {                           // bc
        #pragma unroll
        for (int r = 0; r < 8; ++r) {
            const int i = tid + r * 256;
            bc[i] = (i < 1024) ? (bih_f[i] + bhh_f[i]) : (bih_b[i - 1024] + bhh_b[i - 1024]);
        }
    }
}

// ---------------------------------------------------------------------------
// Persistent BiLSTM recurrence — mailbox exchange, 2 blocks/CU.
// 512 blocks x 1024 thr (VGPR<=64 via launch_bounds(1024,8) => guaranteed
// 2/CU residency; REQUIRED for group lockstep). group g=blk&31 ->
// (d=g>>4, bg=g&15: 2 batches); member mg=blk>>5 (m-slice of 16). All 16
// members of a group share blk%8 -> same XCD under round-robin dispatch.
// Waves 0-7: e k-slices; 8-15: h k-slices (k = wave*32 fused).
// h exchange: self-validating u64 mailbox {tag=s+1, h bits}, relaxed agent
// atomics; 1 u64 poll per lane (data IS the flag). Parity dbuf overrun-safe.
// part layout: [buf][b][gate][m*20 + (wave^(m&3))], gate stride 324:
//   - slot XOR within quads: pairwise-tree sums invariant -> h BIT-IDENTICAL
//     to round 9 (no numeric re-roll); write conflicts 8-way -> 2-way (free).
// ---------------------------------------------------------------------------
__global__ __launch_bounds__(1024, 8) void lstm_rec(
    const float* __restrict__ E,      // [8192 rows t*32+b][256]
    const float* __restrict__ Wt,     // [2][512 fused k][1024 j]
    const float* __restrict__ bc,     // [2][1024]
    float* __restrict__ hh,           // [2][256 s][32 b][256 m] (for out_proj)
    unsigned long long* __restrict__ mb) {  // [32 g][2 par][2 b][256 m]
    const int blk = blockIdx.x;
    const int g   = blk & 31;
    const int mg  = blk >> 5;
    const int d   = g >> 4;
    const int bg  = g & 15;
    const int tid = threadIdx.x;
    const int wave = __builtin_amdgcn_readfirstlane(tid >> 6);  // 0..15
    const int lane = tid & 63;
    const bool is_h = wave >= 8;
    const int wh = wave & 7;
    const int kb = wave * 32;                // fused-k base (h: 256+wh*32)
    const int jg = (lane >> 4) * 256 + mg * 16 + (lane & 15);

    // persistent weights: w[i] = Wt[d][kb+i][jg]   (32 VGPRs)
    float w[32];
    {
        const float* wsrc = Wt + ((size_t)d * 512 + kb) * 1024 + jg;
        #pragma unroll
        for (int i = 0; i < 32; ++i) w[i] = wsrc[(size_t)i * 1024];
    }

    __shared__ __align__(16) float part[2][2][4][324];  // [buf][b][gate][m*20+slot]
    __shared__ __align__(16) float st_e[2][2][256];     // dbuf e activations
    __shared__ __align__(16) float hst[8][2][32];       // per-h-wave ministage
    __shared__ float cst[2][16];
    __shared__ float bias[64];
    if (tid < 64) bias[tid] = bc[d * 1024 + (tid >> 4) * 256 + mg * 16 + (tid & 15)];

    const int b_l = wave & 1;                     // e-stage batch slot
    const int so  = ((wave >> 1) & 3) * 64 + lane; // element offset in 256 row
    const size_t erow = (size_t)(bg * 2 + b_l) * 256 + so;

    // ---- prologue: stage st_e[0](t0), st_e[1](t1); compute part[0] ----
    if (!is_h) {
        const int t0 = d ? (S_LEN - 1) : 0;
        const int t1 = d ? (S_LEN - 2) : 1;
        st_e[0][b_l][so] = E[(size_t)t0 * 8192 + erow];
        st_e[1][b_l][so] = E[(size_t)t1 * 8192 + erow];
    }
    __syncthreads();
    {
        float a0 = 0.f, a1 = 0.f;
        if (!is_h) {
            #pragma unroll 2
            for (int i = 0; i < 8; ++i) {
                const float4 v0 = *(const float4*)&st_e[0][0][kb + i * 4];
                const float4 v1 = *(const float4*)&st_e[0][1][kb + i * 4];
                a0 = fmaf(v0.x, w[i*4+0], a0); a0 = fmaf(v0.y, w[i*4+1], a0);
                a0 = fmaf(v0.z, w[i*4+2], a0); a0 = fmaf(v0.w, w[i*4+3], a0);
                a1 = fmaf(v1.x, w[i*4+0], a1); a1 = fmaf(v1.y, w[i*4+1], a1);
                a1 = fmaf(v1.z, w[i*4+2], a1); a1 = fmaf(v1.w, w[i*4+3], a1);
            }
        }
        const int gq = lane >> 4, m = lane & 15;
        const int slot = wave ^ (m & 3);
        part[0][0][gq][m * 20 + slot] = a0;
        part[0][1][gq][m * 20 + slot] = a1;
    }

    #pragma unroll 1
    for (int s = 0; s < S_LEN; ++s) {
        __syncthreads();                       // part[pc] + st_e[pn] sealed
        const int pc = s & 1, pn = pc ^ 1;

        // ---- lanes 0-31 of wave0: post(s); mailbox store = earliest signal ----
        if (tid < 32) {
            const int bl = tid >> 4, m = tid & 15;
            float vg[4];
            #pragma unroll
            for (int gg = 0; gg < 4; ++gg) {
                const float* pb = &part[pc][bl][gg][m * 20];
                const float4 p0 = *(const float4*)(pb + 0);
                const float4 p1 = *(const float4*)(pb + 4);
                const float4 p2 = *(const float4*)(pb + 8);
                const float4 p3 = *(const float4*)(pb + 12);
                vg[gg] = bias[gg * 16 + m]
                       + ((((p0.x + p0.y) + (p0.z + p0.w)) + ((p1.x + p1.y) + (p1.z + p1.w)))
                        + (((p2.x + p2.y) + (p2.z + p2.w)) + ((p3.x + p3.y) + (p3.z + p3.w))));
            }
            const float iv = sigf(vg[0]);
            const float fv = sigf(vg[1]);
            const float gv = tanhf(vg[2]);
            const float ov = sigf(vg[3]);
            float c = (s == 0) ? 0.f : cst[bl][m];
            c = fv * c + iv * gv;
            cst[bl][m] = c;
            const float hv = ov * tanhf(c);
            if (s < S_LEN - 1) {
                const unsigned long long pv =
                    ((unsigned long long)(unsigned)(s + 1) << 32) |
                    (unsigned long long)__float_as_uint(hv);
                __hip_atomic_store(
                    &mb[(((size_t)g * 2 + ((s + 1) & 1)) * 2 + bl) * 256 + mg * 16 + m],
                    pv, __ATOMIC_RELAXED, __HIP_MEMORY_SCOPE_AGENT);
            }
            hh[(((size_t)d * S_LEN + s) * 32 + (bg * 2 + bl)) * 256 + mg * 16 + m] = hv;
        }

        if (s < S_LEN - 1) {
            float a0 = 0.f, a1 = 0.f;
            if (!is_h) {
                // e-part of step s+1 from LDS (staged one step ago)
                #pragma unroll 2
                for (int i = 0; i < 8; ++i) {
                    const float4 v0 = *(const float4*)&st_e[pn][0][kb + i * 4];
                    const float4 v1 = *(const float4*)&st_e[pn][1][kb + i * 4];
                    a0 = fmaf(v0.x, w[i*4+0], a0); a0 = fmaf(v0.y, w[i*4+1], a0);
                    a0 = fmaf(v0.z, w[i*4+2], a0); a0 = fmaf(v0.w, w[i*4+3], a0);
                    a1 = fmaf(v1.x, w[i*4+0], a1); a1 = fmaf(v1.y, w[i*4+1], a1);
                    a1 = fmaf(v1.z, w[i*4+2], a1); a1 = fmaf(v1.w, w[i*4+3], a1);
                }
                // stage e for step s+2 (consumed after the next barrier)
                if (s + 2 < S_LEN) {
                    const int t2 = d ? (S_LEN - 3 - s) : (s + 2);
                    st_e[pc][b_l][so] = E[(size_t)t2 * 8192 + erow];
                }
            } else {
                // 1 u64 poll per lane: tag match == data ready
                const unsigned tgt = (unsigned)(s + 1);
                const int bl2 = lane >> 5, kk = lane & 31;
                const size_t base = (((size_t)g * 2 + ((s + 1) & 1)) * 2 + bl2) * 256
                                    + wh * 32 + kk;
                unsigned long long v;
                while (true) {
                    v = __hip_atomic_load(&mb[base], __ATOMIC_RELAXED, __HIP_MEMORY_SCOPE_AGENT);
                    if (__all((int)((unsigned)(v >> 32) == tgt))) break;
                }
                hst[wh][bl2][kk] = __uint_as_float((unsigned)v);
                #pragma unroll 2
                for (int i = 0; i < 8; ++i) {
                    const float4 v0 = *(const float4*)&hst[wh][0][i * 4];  // uniform
                    const float4 v1 = *(const float4*)&hst[wh][1][i * 4];
                    a0 = fmaf(v0.x, w[i*4+0], a0); a0 = fmaf(v0.y, w[i*4+1], a0);
                    a0 = fmaf(v0.z, w[i*4+2], a0); a0 = fmaf(v0.w, w[i*4+3], a0);
                    a1 = fmaf(v1.x, w[i*4+0], a1); a1 = fmaf(v1.y, w[i*4+1], a1);
                    a1 = fmaf(v1.z, w[i*4+2], a1); a1 = fmaf(v1.w, w[i*4+3], a1);
                }
            }
            const int gq = lane >> 4, m = lane & 15;
            const int slot = wave ^ (m & 3);
            part[pn][0][gq][m * 20 + slot] = a0;
            part[pn][1][gq][m * 20 + slot] = a1;
        }
    }
}

// ---------------------------------------------------------------------------
// out[r][tag] = [hf | hb] . Wout[tag] + bout[tag],  r = b*256 + t
// ---------------------------------------------------------------------------
__global__ __launch_bounds__(128) void out_proj(const float* __restrict__ hh,
                                                const float* __restrict__ Wout,
                                                const float* __restrict__ bout,
                                                float* __restrict__ out) {
    const int r = blockIdx.x * blockDim.x + threadIdx.x; // 0..8191
    const int b = r >> 8, t = r & 255;
    const float* hf = hh + (((size_t)0 * S_LEN + t) * 32 + b) * 256;
    const float* hb = hh + (((size_t)1 * S_LEN + (S_LEN - 1 - t)) * 32 + b) * 256;
    float acc[NTAG];
    #pragma unroll
    for (int q = 0; q < NTAG; ++q) acc[q] = bout[q];
    for (int m = 0; m < HID; ++m) {
        const float hv = hf[m];
        #pragma unroll
        for (int q = 0; q < NTAG; ++q) acc[q] = fmaf(hv, Wout[q * 512 + m], acc[q]);
    }
    for (int m = 0; m < HID; ++m) {
        const float hv = hb[m];
        #pragma unroll
        for (int q = 0; q < NTAG; ++q) acc[q] = fmaf(hv, Wout[q * 512 + 256 + m], acc[q]);
    }
    #pragma unroll
    for (int q = 0; q < NTAG; ++q) out[(size_t)r * NTAG + q] = acc[q];
}

// ---------------------------------------------------------------------------
// Viterbi forward values (exact reference arithmetic per step). ALL 64 lanes
// run the chain (lanes>=10 carry -inf harmlessly): no exec-mask toggles in
// the serial loop. fvh stored stride-64 (unmasked 256B store). readlane
// broadcast; max3-shaped tree; feats prefetched 8 deep (clamped lane addr).
// ---------------------------------------------------------------------------
__global__ __launch_bounds__(64) void viterbi_fv(const float* __restrict__ feats,
                                                 const float* __restrict__ trans,
                                                 float* __restrict__ fvh64,
                                                 float* __restrict__ score_out,
                                                 int* __restrict__ best_out) {
    const int lane = threadIdx.x;
    const int flane = (lane < NTAG) ? lane : (NTAG - 1);
    float trow[NTAG];
    #pragma unroll
    for (int f = 0; f < NTAG; ++f)
        trow[f] = (lane < NTAG) ? trans[lane * NTAG + f] : -3.0e38f;
    float fv[NTAG];
    #pragma unroll
    for (int f = 0; f < NTAG; ++f) fv[f] = (f == SOS_I) ? 0.f : NEGV;
    float fq[8];
    #pragma unroll
    for (int q = 0; q < 8; ++q) fq[q] = feats[q * NTAG + flane];

    for (int r8 = 0; r8 < L_TOT; r8 += 8) {
        #pragma unroll
        for (int q = 0; q < 8; ++q) {
            const int r = r8 + q;
            float sc[NTAG];
            #pragma unroll
            for (int f = 0; f < NTAG; ++f) sc[f] = fv[f] + trow[f];
            const float m1 = fmaxf(fmaxf(sc[0], sc[1]), sc[2]);
            const float m2 = fmaxf(fmaxf(sc[3], sc[4]), sc[5]);
            const float m3 = fmaxf(fmaxf(sc[6], sc[7]), sc[8]);
            const float mv = fmaxf(fmaxf(fmaxf(m1, m2), m3), sc[9]);
            const float fvnew = mv + fq[q];
            fvh64[(size_t)r * 64 + lane] = fvnew;      // unmasked, coalesced
            const int rn = r + 8;
            if (rn < L_TOT) fq[q] = feats[(size_t)rn * NTAG + flane];
            #pragma unroll
            for (int f = 0; f < NTAG; ++f)
                fv[f] = __uint_as_float(__builtin_amdgcn_readlane(__float_as_uint(fvnew), f));
        }
    }

    if (lane == 0) {
        float bm = fv[0] + trans[EOS_I * NTAG + 0];
        int ba = 0;
        #pragma unroll
        for (int f = 1; f < NTAG; ++f) {
            const float tv = fv[f] + trans[EOS_I * NTAG + f];
            if (tv > bm) { bm = tv; ba = f; }   // strict > => first-max tie rule
        }
        score_out[0] = bm;
        best_out[0] = ba;
    }
}

// Backpointers, fully parallel, packed 4 steps/dword (reads stride-64 fvh)
__global__ __launch_bounds__(256) void viterbi_bp(const float* __restrict__ fvh64,
                                                  const float* __restrict__ trans,
                                                  unsigned int* __restrict__ bp4) {
    const int idx = blockIdx.x * blockDim.x + threadIdx.x;
    if (idx >= (L_TOT / 4) * NTAG) return;
    const int quad = idx / NTAG, to = idx - quad * NTAG;
    float trow[NTAG];
    #pragma unroll
    for (int f = 0; f < NTAG; ++f) trow[f] = trans[to * NTAG + f];
    unsigned pk = 0;
    #pragma unroll
    for (int q = 0; q < 4; ++q) {
        const int r = quad * 4 + q;
        float best = 0.f;
        int arg = 0;
        #pragma unroll
        for (int f = 0; f < NTAG; ++f) {
            const float fp = r ? fvh64[(size_t)(r - 1) * 64 + f]
                               : ((f == SOS_I) ? 0.f : NEGV);
            const float s = fp + trow[f];
            if (f == 0) best = s;
            else if (s > best) { best = s; arg = f; }  // strict > => first-max
        }
        pk |= (unsigned)arg << (q * 8);
    }
    bp4[(size_t)quad * NTAG + to] = pk;
}

// Chunked backtrace (exact function-composition scan over [10]->[10] maps).
__device__ __forceinline__ int bp_at(const unsigned int* bp4, int t, int tag) {
    return (int)((bp4[(size_t)(t >> 2) * NTAG + tag] >> ((t & 3) * 8)) & 0xffu);
}

__global__ __launch_bounds__(1024) void backtrace(const unsigned int* __restrict__ bp4,
                                                  const int* __restrict__ best_in,
                                                  float* __restrict__ path_out) {
    __shared__ unsigned char fc[128 * NTAG];
    __shared__ unsigned char topt[128];
    const int tid = threadIdx.x;
    for (int pe = tid; pe < 128 * NTAG; pe += 1024) {
        const int c = pe / NTAG, e = pe - c * NTAG;
        int cur = e;
        for (int i = 63; i >= 0; --i) cur = bp_at(bp4, c * 64 + i, cur);
        fc[c * NTAG + e] = (unsigned char)cur;
    }
    __syncthreads();
    if (tid == 0) {
        int carry = best_in[0];
        for (int c = 127; c >= 0; --c) {
            topt[c] = (unsigned char)carry;
            carry = fc[c * NTAG + carry];
        }
    }
    __syncthreads();
    for (int c = tid; c < 128; c += 1024) {
        int cur = topt[c];
        for (int i = 63; i >= 0; --i) {
            const int t = c * 64 + i;
            path_out[t] = (float)cur;
            cur = bp_at(bp4, t, cur);
        }
    }
}

// ---------------------------------------------------------------------------
extern "C" void kernel_launch(void* const* d_in, const int* in_sizes, int n_in,
                              void* d_out, int out_size, void* d_ws, size_t ws_size,
                              hipStream_t stream) {
    const int*   x     = (const int*)d_in[0];
    const float* emb   = (const float*)d_in[3];
    const float* Wih_f = (const float*)d_in[4];
    const float* Whh_f = (const float*)d_in[5];
    const float* bih_f = (const float*)d_in[6];
    const float* bhh_f = (const float*)d_in[7];
    const float* Wih_b = (const float*)d_in[8];
    const float* Whh_b = (const float*)d_in[9];
    const float* bih_b = (const float*)d_in[10];
    const float* bhh_b = (const float*)d_in[11];
    const float* Wout  = (const float*)d_in[12];
    const float* bout  = (const float*)d_in[13];
    const float* trans = (const float*)d_in[14];

    char* ws = (char*)d_ws;
    size_t off = 0;
    auto alloc = [&](size_t bytes) { void* p = ws + off; off += (bytes + 255) & ~(size_t)255; return p; };
    const size_t MB_BYTES = (size_t)32 * 2 * 2 * 256 * 8;                 // 256 KB
    unsigned long long* mb = (unsigned long long*)alloc(MB_BYTES);
    int*           best  = (int*)alloc(256);
    float*         E     = (float*)alloc((size_t)L_TOT * EMBD * 4);       // 8.4 MB
    float*         Wt    = (float*)alloc((size_t)2 * 512 * 1024 * 4);     // 4 MB
    float*         bc    = (float*)alloc(2048 * 4);
    float*         hh    = (float*)alloc((size_t)2 * S_LEN * BB * HID * 4); // 16.8 MB
    float*         fvh64 = (float*)alloc((size_t)L_TOT * 64 * 4);         // 2 MB
    unsigned*      bp4   = (unsigned*)alloc((size_t)(L_TOT / 4) * NTAG * 4); // 80 KB

    float* out   = (float*)d_out;                  // [0 .. 81920)
    float* score = out + (size_t)L_TOT * NTAG;     // [81920]
    float* path  = score + 1;                      // [81921 .. 90113)

    (void)hipMemsetAsync(mb, 0, MB_BYTES, stream);  // kill cross-replay stale tags
    hipLaunchKernelGGL(prep_all,  dim3(12289), dim3(256), 0, stream,
                       x, emb, Wih_f, Whh_f, Wih_b, Whh_b,
                       bih_f, bhh_f, bih_b, bhh_b, E, Wt, bc);
    hipLaunchKernelGGL(lstm_rec,  dim3(512),   dim3(1024), 0, stream, E, Wt, bc, hh, mb);
    hipLaunchKernelGGL(out_proj,  dim3(L_TOT / 128), dim3(128), 0, stream, hh, Wout, bout, out);
    hipLaunchKernelGGL(viterbi_fv, dim3(1),    dim3(64),   0, stream, out, trans, fvh64, score, best);
    hipLaunchKernelGGL(viterbi_bp, dim3(((L_TOT / 4) * NTAG + 255) / 256), dim3(256), 0, stream,
                       fvh64, trans, bp4);
    hipLaunchKernelGGL(backtrace, dim3(1),     dim3(1024), 0, stream, bp4, best, path);
}

// Round 11
// 1387.581 us; speedup vs baseline: 2.4058x; 2.4058x over previous
//
#include <hip/hip_runtime.h>
#include <cstdint>
#include <cstddef>

// Problem constants (match reference)
#define S_LEN 256
#define BB    32
#define EMBD  256
#define HID   256
#define NTAG  10
#define L_TOT (BB*S_LEN)      // 8192 flattened viterbi length
#define NEGV  -10000.0f
#define SOS_I 1
#define EOS_I 2

__device__ __forceinline__ float sigf(float x) { return 1.0f / (1.0f + expf(-x)); }

// ---------------------------------------------------------------------------
// prep_all: fused embedding gather + weight transpose + bias combine.
// blocks [0,8192): E rows; [8192,12288): Wt; 12288: bias.
// ---------------------------------------------------------------------------
__global__ __launch_bounds__(256) void prep_all(
    const int* __restrict__ x, const float* __restrict__ emb,
    const float* __restrict__ Wih_f, const float* __restrict__ Whh_f,
    const float* __restrict__ Wih_b, const float* __restrict__ Whh_b,
    const float* __restrict__ bih_f, const float* __restrict__ bhh_f,
    const float* __restrict__ bih_b, const float* __restrict__ bhh_b,
    float* __restrict__ E, float* __restrict__ Wt, float* __restrict__ bc) {
    const int blk = blockIdx.x;
    const int tid = threadIdx.x;
    if (blk < 8192) {                  // E[t*32+b][m] = emb[x[b][t]][m]
        const int t = blk >> 5, b = blk & 31;
        const int xi = x[b * S_LEN + t];
        E[(size_t)blk * EMBD + tid] = emb[(size_t)xi * EMBD + tid];
    } else if (blk < 8192 + 4096) {    // Wt[d][k][j] (k-major)
        const int idx = blk - 8192;
        const int dk = idx >> 2;       // d*512 + k
        const int d = dk >> 9, k = dk & 511;
        const int j = (idx & 3) * 256 + tid;
        const float* src = (d == 0) ? ((k < 256) ? Wih_f : Whh_f)
                                    : ((k < 256) ? Wih_b : Whh_b);
        Wt[(size_t)dk * 1024 + j] = src[(size_t)j * 256 + (k & 255)];
    } else {                           // bc
        #pragma unroll
        for (int r = 0; r < 8; ++r) {
            const int i = tid + r * 256;
            bc[i] = (i < 1024) ? (bih_f[i] + bhh_f[i]) : (bih_b[i - 1024] + bhh_b[i - 1024]);
        }
    }
}

// ---------------------------------------------------------------------------
// Persistent BiLSTM recurrence — r9 geometry (proven 790us, VGPR 56) +
// bank-clean part layout + corrected full e-restaging + poll s_sleep.
// 256 blocks x 1024 thr (default launch_bounds(1024): 128-VGPR cap; usage
// ~60 -> NO SPILL. Never cap below ~100: r10's cap=64 respilled -> 9GB).
// group g=blk&15 -> (d=g>>3, bg=g&7: 4 batches); member mg=blk>>4 (16 m-slices).
// Waves 0-7: e k-slices; 8-15: h k-slices (k = wave*32 fused).
// h exchange: self-validating u64 mailbox {tag=s+1, h bits}, relaxed agent
// atomics (1-RTT: data IS the flag). Parity dbuf overrun-safe.
// part: float[2][4][1300], idx = gate*324 + m*20 + (wave^(m&3)):
//   writes 2-way max (free); post b128 reads 8-way (structural, ~45cy, ok).
// ---------------------------------------------------------------------------
__global__ __launch_bounds__(1024) void lstm_rec(
    const float* __restrict__ E,      // [8192 rows t*32+b][256]
    const float* __restrict__ Wt,     // [2][512 fused k][1024 j]
    const float* __restrict__ bc,     // [2][1024]
    float* __restrict__ hh,           // [2][256 s][32 b][256 m] (for out_proj)
    unsigned long long* __restrict__ mb) {  // [16 g][2 par][4 b][256 m]
    const int blk = blockIdx.x;
    const int g   = blk & 15;
    const int mg  = blk >> 4;
    const int d   = g >> 3;
    const int bg  = g & 7;
    const int tid = threadIdx.x;
    const int wave = __builtin_amdgcn_readfirstlane(tid >> 6);  // 0..15
    const int lane = tid & 63;
    const bool is_h = wave >= 8;
    const int wh = wave & 7;
    const int kb = wave * 32;                // fused-k base (h: 256+wh*32)
    const int jg = (lane >> 4) * 256 + mg * 16 + (lane & 15);

    // persistent weights: w[i] = Wt[d][kb+i][jg]   (32 VGPRs)
    float w[32];
    {
        const float* wsrc = Wt + ((size_t)d * 512 + kb) * 1024 + jg;
        #pragma unroll
        for (int i = 0; i < 32; ++i) w[i] = wsrc[(size_t)i * 1024];
    }

    __shared__ __align__(16) float part[2][4][1300];  // [buf][b][g*324 + m*20 + slot]
    __shared__ __align__(16) float st_e[2][4][256];   // dbuf e activations
    __shared__ __align__(16) float hst[8][4][32];     // per-h-wave ministage
    __shared__ float cst[4][16];
    __shared__ float bias[64];
    if (tid < 64) bias[tid] = bc[d * 1024 + (tid >> 4) * 256 + mg * 16 + (tid & 15)];

    // prologue staging mapping: all 16 waves, 1 float/lane covers 4b x 256
    const int pb_l = wave & 3;                 // prologue batch slot
    const int pso  = (wave >> 2) * 64 + lane;  // prologue element offset
    // in-loop staging mapping: 8 e-waves, float2/lane covers 4b x 256
    const int sb_l = wave & 3;                 // e-wave batch slot (waves 0-7)
    const int sh   = (wave >> 2) & 1;          // which 128-half
    const int soff = sh * 128 + lane * 2;      // float2 offset

    // ---- prologue: stage st_e[0](t0), st_e[1](t1); compute part[0] ----
    {
        const int t0 = d ? (S_LEN - 1) : 0;
        const int t1 = d ? (S_LEN - 2) : 1;
        const size_t er = (size_t)(bg * 4 + pb_l) * 256 + pso;
        st_e[0][pb_l][pso] = E[(size_t)t0 * 8192 + er];
        st_e[1][pb_l][pso] = E[(size_t)t1 * 8192 + er];
    }
    __syncthreads();
    {
        float acc[4] = {0.f, 0.f, 0.f, 0.f};
        if (!is_h) {
            #pragma unroll 2
            for (int i = 0; i < 8; ++i) {
                #pragma unroll
                for (int b = 0; b < 4; ++b) {
                    const float4 v = *(const float4*)&st_e[0][b][kb + i * 4];
                    acc[b] = fmaf(v.x, w[i*4+0], acc[b]); acc[b] = fmaf(v.y, w[i*4+1], acc[b]);
                    acc[b] = fmaf(v.z, w[i*4+2], acc[b]); acc[b] = fmaf(v.w, w[i*4+3], acc[b]);
                }
            }
        }
        const int gq = lane >> 4, m = lane & 15;
        const int pidx = gq * 324 + m * 20 + (wave ^ (m & 3));
        #pragma unroll
        for (int b = 0; b < 4; ++b) part[0][b][pidx] = acc[b];
    }

    #pragma unroll 1
    for (int s = 0; s < S_LEN; ++s) {
        __syncthreads();                       // part[pc] + st_e[pn] sealed
        const int pc = s & 1, pn = pc ^ 1;

        // ---- wave0 (64 lanes = 4b x 16m): post(s); mailbox = earliest signal ----
        if (tid < 64) {
            const int bl = tid >> 4, m = tid & 15;
            float vg[4];
            #pragma unroll
            for (int gg = 0; gg < 4; ++gg) {
                const float* pb = &part[pc][bl][gg * 324 + m * 20];
                const float4 p0 = *(const float4*)(pb + 0);
                const float4 p1 = *(const float4*)(pb + 4);
                const float4 p2 = *(const float4*)(pb + 8);
                const float4 p3 = *(const float4*)(pb + 12);
                vg[gg] = bias[gg * 16 + m]
                       + ((((p0.x + p0.y) + (p0.z + p0.w)) + ((p1.x + p1.y) + (p1.z + p1.w)))
                        + (((p2.x + p2.y) + (p2.z + p2.w)) + ((p3.x + p3.y) + (p3.z + p3.w))));
            }
            const float iv = sigf(vg[0]);
            const float fv = sigf(vg[1]);
            const float gv = tanhf(vg[2]);
            const float ov = sigf(vg[3]);
            float c = (s == 0) ? 0.f : cst[bl][m];
            c = fv * c + iv * gv;
            cst[bl][m] = c;
            const float hv = ov * tanhf(c);
            if (s < S_LEN - 1) {
                const unsigned long long pv =
                    ((unsigned long long)(unsigned)(s + 1) << 32) |
                    (unsigned long long)__float_as_uint(hv);
                __hip_atomic_store(
                    &mb[(((size_t)g * 2 + ((s + 1) & 1)) * 4 + bl) * 256 + mg * 16 + m],
                    pv, __ATOMIC_RELAXED, __HIP_MEMORY_SCOPE_AGENT);
            }
            hh[(((size_t)d * S_LEN + s) * 32 + (bg * 4 + bl)) * 256 + mg * 16 + m] = hv;
        }

        if (s < S_LEN - 1) {
            float acc[4] = {0.f, 0.f, 0.f, 0.f};
            if (!is_h) {
                // e-part of step s+1 from LDS (staged one step ago)
                #pragma unroll 2
                for (int i = 0; i < 8; ++i) {
                    #pragma unroll
                    for (int b = 0; b < 4; ++b) {
                        const float4 v = *(const float4*)&st_e[pn][b][kb + i * 4];
                        acc[b] = fmaf(v.x, w[i*4+0], acc[b]); acc[b] = fmaf(v.y, w[i*4+1], acc[b]);
                        acc[b] = fmaf(v.z, w[i*4+2], acc[b]); acc[b] = fmaf(v.w, w[i*4+3], acc[b]);
                    }
                }
                // stage e for step s+2: float2/lane -> FULL 4b x 256 coverage
                // (r9 covered only k<128 here -> stale upper half, absmax 0.066)
                if (s + 2 < S_LEN) {
                    const int t2 = d ? (S_LEN - 3 - s) : (s + 2);
                    const size_t er = (size_t)(bg * 4 + sb_l) * 256 + soff;
                    *(float2*)&st_e[pc][sb_l][soff] =
                        *(const float2*)(E + (size_t)t2 * 8192 + er);
                }
            } else {
                // poll own 2 payload words; tag match == data ready
                const unsigned tgt = (unsigned)(s + 1);
                const int bl2 = lane >> 4, kk = (lane & 15) * 2;
                const size_t base = (((size_t)g * 2 + ((s + 1) & 1)) * 4 + bl2) * 256
                                    + wh * 32 + kk;
                unsigned long long a, b;
                while (true) {
                    a = __hip_atomic_load(&mb[base],     __ATOMIC_RELAXED, __HIP_MEMORY_SCOPE_AGENT);
                    b = __hip_atomic_load(&mb[base + 1], __ATOMIC_RELAXED, __HIP_MEMORY_SCOPE_AGENT);
                    const bool ok = ((unsigned)(a >> 32) == tgt) && ((unsigned)(b >> 32) == tgt);
                    if (__all((int)ok)) break;
                    __builtin_amdgcn_s_sleep(1);
                }
                hst[wh][bl2][kk]     = __uint_as_float((unsigned)a);
                hst[wh][bl2][kk + 1] = __uint_as_float((unsigned)b);
                #pragma unroll 2
                for (int i = 0; i < 8; ++i) {
                    #pragma unroll
                    for (int b4 = 0; b4 < 4; ++b4) {
                        const float4 v = *(const float4*)&hst[wh][b4][i * 4];  // uniform
                        acc[b4] = fmaf(v.x, w[i*4+0], acc[b4]); acc[b4] = fmaf(v.y, w[i*4+1], acc[b4]);
                        acc[b4] = fmaf(v.z, w[i*4+2], acc[b4]); acc[b4] = fmaf(v.w, w[i*4+3], acc[b4]);
                    }
                }
            }
            const int gq = lane >> 4, m = lane & 15;
            const int pidx = gq * 324 + m * 20 + (wave ^ (m & 3));
            #pragma unroll
            for (int b = 0; b < 4; ++b) part[pn][b][pidx] = acc[b];
        }
    }
}

// ---------------------------------------------------------------------------
// out[r][tag] = [hf | hb] . Wout[tag] + bout[tag],  r = b*256 + t
// ---------------------------------------------------------------------------
__global__ __launch_bounds__(128) void out_proj(const float* __restrict__ hh,
                                                const float* __restrict__ Wout,
                                                const float* __restrict__ bout,
                                                float* __restrict__ out) {
    const int r = blockIdx.x * blockDim.x + threadIdx.x; // 0..8191
    const int b = r >> 8, t = r & 255;
    const float* hf = hh + (((size_t)0 * S_LEN + t) * 32 + b) * 256;
    const float* hb = hh + (((size_t)1 * S_LEN + (S_LEN - 1 - t)) * 32 + b) * 256;
    float acc[NTAG];
    #pragma unroll
    for (int q = 0; q < NTAG; ++q) acc[q] = bout[q];
    for (int m = 0; m < HID; ++m) {
        const float hv = hf[m];
        #pragma unroll
        for (int q = 0; q < NTAG; ++q) acc[q] = fmaf(hv, Wout[q * 512 + m], acc[q]);
    }
    for (int m = 0; m < HID; ++m) {
        const float hv = hb[m];
        #pragma unroll
        for (int q = 0; q < NTAG; ++q) acc[q] = fmaf(hv, Wout[q * 512 + 256 + m], acc[q]);
    }
    #pragma unroll
    for (int q = 0; q < NTAG; ++q) out[(size_t)r * NTAG + q] = acc[q];
}

// ---------------------------------------------------------------------------
// Viterbi forward values (exact reference arithmetic per step). ALL 64 lanes
// run the chain (lanes>=10 carry -inf harmlessly). fvh stride-64 unmasked
// store; readlane broadcast; max3-shaped tree; feats prefetched 8 deep.
// ---------------------------------------------------------------------------
__global__ __launch_bounds__(64) void viterbi_fv(const float* __restrict__ feats,
                                                 const float* __restrict__ trans,
                                                 float* __restrict__ fvh64,
                                                 float* __restrict__ score_out,
                                                 int* __restrict__ best_out) {
    const int lane = threadIdx.x;
    const int flane = (lane < NTAG) ? lane : (NTAG - 1);
    float trow[NTAG];
    #pragma unroll
    for (int f = 0; f < NTAG; ++f)
        trow[f] = (lane < NTAG) ? trans[lane * NTAG + f] : -3.0e38f;
    float fv[NTAG];
    #pragma unroll
    for (int f = 0; f < NTAG; ++f) fv[f] = (f == SOS_I) ? 0.f : NEGV;
    float fq[8];
    #pragma unroll
    for (int q = 0; q < 8; ++q) fq[q] = feats[q * NTAG + flane];

    for (int r8 = 0; r8 < L_TOT; r8 += 8) {
        #pragma unroll
        for (int q = 0; q < 8; ++q) {
            const int r = r8 + q;
            float sc[NTAG];
            #pragma unroll
            for (int f = 0; f < NTAG; ++f) sc[f] = fv[f] + trow[f];
            const float m1 = fmaxf(fmaxf(sc[0], sc[1]), sc[2]);
            const float m2 = fmaxf(fmaxf(sc[3], sc[4]), sc[5]);
            const float m3 = fmaxf(fmaxf(sc[6], sc[7]), sc[8]);
            const float mv = fmaxf(fmaxf(fmaxf(m1, m2), m3), sc[9]);
            const float fvnew = mv + fq[q];
            fvh64[(size_t)r * 64 + lane] = fvnew;      // unmasked, coalesced
            const int rn = r + 8;
            if (rn < L_TOT) fq[q] = feats[(size_t)rn * NTAG + flane];
            #pragma unroll
            for (int f = 0; f < NTAG; ++f)
                fv[f] = __uint_as_float(__builtin_amdgcn_readlane(__float_as_uint(fvnew), f));
        }
    }

    if (lane == 0) {
        float bm = fv[0] + trans[EOS_I * NTAG + 0];
        int ba = 0;
        #pragma unroll
        for (int f = 1; f < NTAG; ++f) {
            const float tv = fv[f] + trans[EOS_I * NTAG + f];
            if (tv > bm) { bm = tv; ba = f; }   // strict > => first-max tie rule
        }
        score_out[0] = bm;
        best_out[0] = ba;
    }
}

// Backpointers, fully parallel, packed 4 steps/dword (reads stride-64 fvh)
__global__ __launch_bounds__(256) void viterbi_bp(const float* __restrict__ fvh64,
                                                  const float* __restrict__ trans,
                                                  unsigned int* __restrict__ bp4) {
    const int idx = blockIdx.x * blockDim.x + threadIdx.x;
    if (idx >= (L_TOT / 4) * NTAG) return;
    const int quad = idx / NTAG, to = idx - quad * NTAG;
    float trow[NTAG];
    #pragma unroll
    for (int f = 0; f < NTAG; ++f) trow[f] = trans[to * NTAG + f];
    unsigned pk = 0;
    #pragma unroll
    for (int q = 0; q < 4; ++q) {
        const int r = quad * 4 + q;
        float best = 0.f;
        int arg = 0;
        #pragma unroll
        for (int f = 0; f < NTAG; ++f) {
            const float fp = r ? fvh64[(size_t)(r - 1) * 64 + f]
                               : ((f == SOS_I) ? 0.f : NEGV);
            const float s = fp + trow[f];
            if (f == 0) best = s;
            else if (s > best) { best = s; arg = f; }  // strict > => first-max
        }
        pk |= (unsigned)arg << (q * 8);
    }
    bp4[(size_t)quad * NTAG + to] = pk;
}

// Chunked backtrace (exact function-composition scan over [10]->[10] maps).
__device__ __forceinline__ int bp_at(const unsigned int* bp4, int t, int tag) {
    return (int)((bp4[(size_t)(t >> 2) * NTAG + tag] >> ((t & 3) * 8)) & 0xffu);
}

__global__ __launch_bounds__(1024) void backtrace(const unsigned int* __restrict__ bp4,
                                                  const int* __restrict__ best_in,
                                                  float* __restrict__ path_out) {
    __shared__ unsigned char fc[128 * NTAG];
    __shared__ unsigned char topt[128];
    const int tid = threadIdx.x;
    for (int pe = tid; pe < 128 * NTAG; pe += 1024) {
        const int c = pe / NTAG, e = pe - c * NTAG;
        int cur = e;
        for (int i = 63; i >= 0; --i) cur = bp_at(bp4, c * 64 + i, cur);
        fc[c * NTAG + e] = (unsigned char)cur;
    }
    __syncthreads();
    if (tid == 0) {
        int carry = best_in[0];
        for (int c = 127; c >= 0; --c) {
            topt[c] = (unsigned char)carry;
            carry = fc[c * NTAG + carry];
        }
    }
    __syncthreads();
    for (int c = tid; c < 128; c += 1024) {
        int cur = topt[c];
        for (int i = 63; i >= 0; --i) {
            const int t = c * 64 + i;
            path_out[t] = (float)cur;
            cur = bp_at(bp4, t, cur);
        }
    }
}

// ---------------------------------------------------------------------------
extern "C" void kernel_launch(void* const* d_in, const int* in_sizes, int n_in,
                              void* d_out, int out_size, void* d_ws, size_t ws_size,
                              hipStream_t stream) {
    const int*   x     = (const int*)d_in[0];
    const float* emb   = (const float*)d_in[3];
    const float* Wih_f = (const float*)d_in[4];
    const float* Whh_f = (const float*)d_in[5];
    const float* bih_f = (const float*)d_in[6];
    const float* bhh_f = (const float*)d_in[7];
    const float* Wih_b = (const float*)d_in[8];
    const float* Whh_b = (const float*)d_in[9];
    const float* bih_b = (const float*)d_in[10];
    const float* bhh_b = (const float*)d_in[11];
    const float* Wout  = (const float*)d_in[12];
    const float* bout  = (const float*)d_in[13];
    const float* trans = (const float*)d_in[14];

    char* ws = (char*)d_ws;
    size_t off = 0;
    auto alloc = [&](size_t bytes) { void* p = ws + off; off += (bytes + 255) & ~(size_t)255; return p; };
    const size_t MB_BYTES = (size_t)16 * 2 * 4 * 256 * 8;                 // 256 KB
    unsigned long long* mb = (unsigned long long*)alloc(MB_BYTES);
    int*           best  = (int*)alloc(256);
    float*         E     = (float*)alloc((size_t)L_TOT * EMBD * 4);       // 8.4 MB
    float*         Wt    = (float*)alloc((size_t)2 * 512 * 1024 * 4);     // 4 MB
    float*         bc    = (float*)alloc(2048 * 4);
    float*         hh    = (float*)alloc((size_t)2 * S_LEN * BB * HID * 4); // 16.8 MB
    float*         fvh64 = (float*)alloc((size_t)L_TOT * 64 * 4);         // 2 MB
    unsigned*      bp4   = (unsigned*)alloc((size_t)(L_TOT / 4) * NTAG * 4); // 80 KB

    float* out   = (float*)d_out;                  // [0 .. 81920)
    float* score = out + (size_t)L_TOT * NTAG;     // [81920]
    float* path  = score + 1;                      // [81921 .. 90113)

    (void)hipMemsetAsync(mb, 0, MB_BYTES, stream);  // kill cross-replay stale tags
    hipLaunchKernelGGL(prep_all,  dim3(12289), dim3(256), 0, stream,
                       x, emb, Wih_f, Whh_f, Wih_b, Whh_b,
                       bih_f, bhh_f, bih_b, bhh_b, E, Wt, bc);
    hipLaunchKernelGGL(lstm_rec,  dim3(256),   dim3(1024), 0, stream, E, Wt, bc, hh, mb);
    hipLaunchKernelGGL(out_proj,  dim3(L_TOT / 128), dim3(128), 0, stream, hh, Wout, bout, out);
    hipLaunchKernelGGL(viterbi_fv, dim3(1),    dim3(64),   0, stream, out, trans, fvh64, score, best);
    hipLaunchKernelGGL(viterbi_bp, dim3(((L_TOT / 4) * NTAG + 255) / 256), dim3(256), 0, stream,
                       fvh64, trans, bp4);
    hipLaunchKernelGGL(backtrace, dim3(1),     dim3(1024), 0, stream, bp4, best, path);
}

// Round 12
// 1376.268 us; speedup vs baseline: 2.4255x; 1.0082x over previous
//
#include <hip/hip_runtime.h>
#include <cstdint>
#include <cstddef>

// Problem constants (match reference)
#define S_LEN 256
#define BB    32
#define EMBD  256
#define HID   256
#define NTAG  10
#define L_TOT (BB*S_LEN)      // 8192 flattened viterbi length
#define NEGV  -10000.0f
#define SOS_I 1
#define EOS_I 2

__device__ __forceinline__ float sigf(float x) { return 1.0f / (1.0f + expf(-x)); }

// ---------------------------------------------------------------------------
// prep_all: fused embedding gather + weight transpose + bias combine.
// blocks [0,8192): E rows; [8192,12288): Wt; 12288: bias.
// ---------------------------------------------------------------------------
__global__ __launch_bounds__(256) void prep_all(
    const int* __restrict__ x, const float* __restrict__ emb,
    const float* __restrict__ Wih_f, const float* __restrict__ Whh_f,
    const float* __restrict__ Wih_b, const float* __restrict__ Whh_b,
    const float* __restrict__ bih_f, const float* __restrict__ bhh_f,
    const float* __restrict__ bih_b, const float* __restrict__ bhh_b,
    float* __restrict__ E, float* __restrict__ Wt, float* __restrict__ bc) {
    const int blk = blockIdx.x;
    const int tid = threadIdx.x;
    if (blk < 8192) {                  // E[t*32+b][m] = emb[x[b][t]][m]
        const int t = blk >> 5, b = blk & 31;
        const int xi = x[b * S_LEN + t];
        E[(size_t)blk * EMBD + tid] = emb[(size_t)xi * EMBD + tid];
    } else if (blk < 8192 + 4096) {    // Wt[d][k][j] (k-major)
        const int idx = blk - 8192;
        const int dk = idx >> 2;       // d*512 + k
        const int d = dk >> 9, k = dk & 511;
        const int j = (idx & 3) * 256 + tid;
        const float* src = (d == 0) ? ((k < 256) ? Wih_f : Whh_f)
                                    : ((k < 256) ? Wih_b : Whh_b);
        Wt[(size_t)dk * 1024 + j] = src[(size_t)j * 256 + (k & 255)];
    } else {                           // bc
        #pragma unroll
        for (int r = 0; r < 8; ++r) {
            const int i = tid + r * 256;
            bc[i] = (i < 1024) ? (bih_f[i] + bhh_f[i]) : (bih_b[i - 1024] + bhh_b[i - 1024]);
        }
    }
}

// ---------------------------------------------------------------------------
// Persistent BiLSTM recurrence — r11 structure with two probes:
//   (1) poll backoff s_sleep(8): contention-vs-latency discriminator
//   (2) two-wave post: waves 0,1 each post 2 batches (halves post serial time;
//       self-validating mailbox means no cross-wave ordering needed)
// 256 blocks x 1024 thr (default 128-VGPR cap, usage ~56: NO SPILL; never
// cap below ~100 -- r10's cap=64 respilled -> 9GB).
// group g=blk&15 -> (d=g>>3, bg=g&7: 4 batches); member mg=blk>>4.
// Waves 0-7: e k-slices; 8-15: h k-slices (k = wave*32 fused).
// h exchange: self-validating u64 mailbox {tag=s+1, h bits}, relaxed agent
// atomics (1-RTT: data IS the flag). Parity dbuf overrun-safe.
// ---------------------------------------------------------------------------
__global__ __launch_bounds__(1024) void lstm_rec(
    const float* __restrict__ E,      // [8192 rows t*32+b][256]
    const float* __restrict__ Wt,     // [2][512 fused k][1024 j]
    const float* __restrict__ bc,     // [2][1024]
    float* __restrict__ hh,           // [2][256 s][32 b][256 m] (for out_proj)
    unsigned long long* __restrict__ mb) {  // [16 g][2 par][4 b][256 m]
    const int blk = blockIdx.x;
    const int g   = blk & 15;
    const int mg  = blk >> 4;
    const int d   = g >> 3;
    const int bg  = g & 7;
    const int tid = threadIdx.x;
    const int wave = __builtin_amdgcn_readfirstlane(tid >> 6);  // 0..15
    const int lane = tid & 63;
    const bool is_h = wave >= 8;
    const int wh = wave & 7;
    const int kb = wave * 32;                // fused-k base (h: 256+wh*32)
    const int jg = (lane >> 4) * 256 + mg * 16 + (lane & 15);

    // persistent weights: w[i] = Wt[d][kb+i][jg]   (32 VGPRs)
    float w[32];
    {
        const float* wsrc = Wt + ((size_t)d * 512 + kb) * 1024 + jg;
        #pragma unroll
        for (int i = 0; i < 32; ++i) w[i] = wsrc[(size_t)i * 1024];
    }

    __shared__ __align__(16) float part[2][4][1300];  // [buf][b][g*324 + m*20 + slot]
    __shared__ __align__(16) float st_e[2][4][256];   // dbuf e activations
    __shared__ __align__(16) float hst[8][4][32];     // per-h-wave ministage
    __shared__ float cst[4][16];
    __shared__ float bias[64];
    if (tid < 64) bias[tid] = bc[d * 1024 + (tid >> 4) * 256 + mg * 16 + (tid & 15)];

    // prologue staging mapping: all 16 waves, 1 float/lane covers 4b x 256
    const int pb_l = wave & 3;                 // prologue batch slot
    const int pso  = (wave >> 2) * 64 + lane;  // prologue element offset
    // in-loop staging mapping: 8 e-waves, float2/lane covers 4b x 256
    const int sb_l = wave & 3;                 // e-wave batch slot (waves 0-7)
    const int sh   = (wave >> 2) & 1;          // which 128-half
    const int soff = sh * 128 + lane * 2;      // float2 offset

    // ---- prologue: stage st_e[0](t0), st_e[1](t1); compute part[0] ----
    {
        const int t0 = d ? (S_LEN - 1) : 0;
        const int t1 = d ? (S_LEN - 2) : 1;
        const size_t er = (size_t)(bg * 4 + pb_l) * 256 + pso;
        st_e[0][pb_l][pso] = E[(size_t)t0 * 8192 + er];
        st_e[1][pb_l][pso] = E[(size_t)t1 * 8192 + er];
    }
    __syncthreads();
    {
        float acc[4] = {0.f, 0.f, 0.f, 0.f};
        if (!is_h) {
            #pragma unroll 2
            for (int i = 0; i < 8; ++i) {
                #pragma unroll
                for (int b = 0; b < 4; ++b) {
                    const float4 v = *(const float4*)&st_e[0][b][kb + i * 4];
                    acc[b] = fmaf(v.x, w[i*4+0], acc[b]); acc[b] = fmaf(v.y, w[i*4+1], acc[b]);
                    acc[b] = fmaf(v.z, w[i*4+2], acc[b]); acc[b] = fmaf(v.w, w[i*4+3], acc[b]);
                }
            }
        }
        const int gq = lane >> 4, m = lane & 15;
        const int pidx = gq * 324 + m * 20 + (wave ^ (m & 3));
        #pragma unroll
        for (int b = 0; b < 4; ++b) part[0][b][pidx] = acc[b];
    }

    #pragma unroll 1
    for (int s = 0; s < S_LEN; ++s) {
        __syncthreads();                       // part[pc] + st_e[pn] sealed
        const int pc = s & 1, pn = pc ^ 1;

        // ---- two-wave post(s): wave0 -> batches 0,1; wave1 -> batches 2,3 ----
        if (tid < 128 && lane < 32) {
            const int bl = wave * 2 + (lane >> 4), m = lane & 15;
            float vg[4];
            #pragma unroll
            for (int gg = 0; gg < 4; ++gg) {
                const float* pb = &part[pc][bl][gg * 324 + m * 20];
                const float4 p0 = *(const float4*)(pb + 0);
                const float4 p1 = *(const float4*)(pb + 4);
                const float4 p2 = *(const float4*)(pb + 8);
                const float4 p3 = *(const float4*)(pb + 12);
                vg[gg] = bias[gg * 16 + m]
                       + ((((p0.x + p0.y) + (p0.z + p0.w)) + ((p1.x + p1.y) + (p1.z + p1.w)))
                        + (((p2.x + p2.y) + (p2.z + p2.w)) + ((p3.x + p3.y) + (p3.z + p3.w))));
            }
            const float iv = sigf(vg[0]);
            const float fv = sigf(vg[1]);
            const float gv = tanhf(vg[2]);
            const float ov = sigf(vg[3]);
            float c = (s == 0) ? 0.f : cst[bl][m];
            c = fv * c + iv * gv;
            cst[bl][m] = c;
            const float hv = ov * tanhf(c);
            if (s < S_LEN - 1) {
                const unsigned long long pv =
                    ((unsigned long long)(unsigned)(s + 1) << 32) |
                    (unsigned long long)__float_as_uint(hv);
                __hip_atomic_store(
                    &mb[(((size_t)g * 2 + ((s + 1) & 1)) * 4 + bl) * 256 + mg * 16 + m],
                    pv, __ATOMIC_RELAXED, __HIP_MEMORY_SCOPE_AGENT);
            }
            hh[(((size_t)d * S_LEN + s) * 32 + (bg * 4 + bl)) * 256 + mg * 16 + m] = hv;
        }

        if (s < S_LEN - 1) {
            float acc[4] = {0.f, 0.f, 0.f, 0.f};
            if (!is_h) {
                // e-part of step s+1 from LDS (staged one step ago)
                #pragma unroll 2
                for (int i = 0; i < 8; ++i) {
                    #pragma unroll
                    for (int b = 0; b < 4; ++b) {
                        const float4 v = *(const float4*)&st_e[pn][b][kb + i * 4];
                        acc[b] = fmaf(v.x, w[i*4+0], acc[b]); acc[b] = fmaf(v.y, w[i*4+1], acc[b]);
                        acc[b] = fmaf(v.z, w[i*4+2], acc[b]); acc[b] = fmaf(v.w, w[i*4+3], acc[b]);
                    }
                }
                // stage e for step s+2 (full 4b x 256 coverage: float2/lane)
                if (s + 2 < S_LEN) {
                    const int t2 = d ? (S_LEN - 3 - s) : (s + 2);
                    const size_t er = (size_t)(bg * 4 + sb_l) * 256 + soff;
                    *(float2*)&st_e[pc][sb_l][soff] =
                        *(const float2*)(E + (size_t)t2 * 8192 + er);
                }
            } else {
                // poll own 2 payload words; tag match == data ready.
                // s_sleep(8) backoff: probe for fabric contention (r12).
                const unsigned tgt = (unsigned)(s + 1);
                const int bl2 = lane >> 4, kk = (lane & 15) * 2;
                const size_t base = (((size_t)g * 2 + ((s + 1) & 1)) * 4 + bl2) * 256
                                    + wh * 32 + kk;
                unsigned long long a, b;
                while (true) {
                    a = __hip_atomic_load(&mb[base],     __ATOMIC_RELAXED, __HIP_MEMORY_SCOPE_AGENT);
                    b = __hip_atomic_load(&mb[base + 1], __ATOMIC_RELAXED, __HIP_MEMORY_SCOPE_AGENT);
                    const bool ok = ((unsigned)(a >> 32) == tgt) && ((unsigned)(b >> 32) == tgt);
                    if (__all((int)ok)) break;
                    __builtin_amdgcn_s_sleep(8);
                }
                hst[wh][bl2][kk]     = __uint_as_float((unsigned)a);
                hst[wh][bl2][kk + 1] = __uint_as_float((unsigned)b);
                #pragma unroll 2
                for (int i = 0; i < 8; ++i) {
                    #pragma unroll
                    for (int b4 = 0; b4 < 4; ++b4) {
                        const float4 v = *(const float4*)&hst[wh][b4][i * 4];  // uniform
                        acc[b4] = fmaf(v.x, w[i*4+0], acc[b4]); acc[b4] = fmaf(v.y, w[i*4+1], acc[b4]);
                        acc[b4] = fmaf(v.z, w[i*4+2], acc[b4]); acc[b4] = fmaf(v.w, w[i*4+3], acc[b4]);
                    }
                }
            }
            const int gq = lane >> 4, m = lane & 15;
            const int pidx = gq * 324 + m * 20 + (wave ^ (m & 3));
            #pragma unroll
            for (int b = 0; b < 4; ++b) part[pn][b][pidx] = acc[b];
        }
    }
}

// ---------------------------------------------------------------------------
// out[r][tag] = [hf | hb] . Wout[tag] + bout[tag],  r = b*256 + t
// ---------------------------------------------------------------------------
__global__ __launch_bounds__(128) void out_proj(const float* __restrict__ hh,
                                                const float* __restrict__ Wout,
                                                const float* __restrict__ bout,
                                                float* __restrict__ out) {
    const int r = blockIdx.x * blockDim.x + threadIdx.x; // 0..8191
    const int b = r >> 8, t = r & 255;
    const float* hf = hh + (((size_t)0 * S_LEN + t) * 32 + b) * 256;
    const float* hb = hh + (((size_t)1 * S_LEN + (S_LEN - 1 - t)) * 32 + b) * 256;
    float acc[NTAG];
    #pragma unroll
    for (int q = 0; q < NTAG; ++q) acc[q] = bout[q];
    for (int m = 0; m < HID; ++m) {
        const float hv = hf[m];
        #pragma unroll
        for (int q = 0; q < NTAG; ++q) acc[q] = fmaf(hv, Wout[q * 512 + m], acc[q]);
    }
    for (int m = 0; m < HID; ++m) {
        const float hv = hb[m];
        #pragma unroll
        for (int q = 0; q < NTAG; ++q) acc[q] = fmaf(hv, Wout[q * 512 + 256 + m], acc[q]);
    }
    #pragma unroll
    for (int q = 0; q < NTAG; ++q) out[(size_t)r * NTAG + q] = acc[q];
}

// ---------------------------------------------------------------------------
// Viterbi forward values (exact reference arithmetic per step). ALL 64 lanes
// run the chain (lanes>=10 carry -inf harmlessly). fvh stride-64 unmasked
// store; readlane broadcast; max3-shaped tree; feats prefetched 8 deep.
// ---------------------------------------------------------------------------
__global__ __launch_bounds__(64) void viterbi_fv(const float* __restrict__ feats,
                                                 const float* __restrict__ trans,
                                                 float* __restrict__ fvh64,
                                                 float* __restrict__ score_out,
                                                 int* __restrict__ best_out) {
    const int lane = threadIdx.x;
    const int flane = (lane < NTAG) ? lane : (NTAG - 1);
    float trow[NTAG];
    #pragma unroll
    for (int f = 0; f < NTAG; ++f)
        trow[f] = (lane < NTAG) ? trans[lane * NTAG + f] : -3.0e38f;
    float fv[NTAG];
    #pragma unroll
    for (int f = 0; f < NTAG; ++f) fv[f] = (f == SOS_I) ? 0.f : NEGV;
    float fq[8];
    #pragma unroll
    for (int q = 0; q < 8; ++q) fq[q] = feats[q * NTAG + flane];

    for (int r8 = 0; r8 < L_TOT; r8 += 8) {
        #pragma unroll
        for (int q = 0; q < 8; ++q) {
            const int r = r8 + q;
            float sc[NTAG];
            #pragma unroll
            for (int f = 0; f < NTAG; ++f) sc[f] = fv[f] + trow[f];
            const float m1 = fmaxf(fmaxf(sc[0], sc[1]), sc[2]);
            const float m2 = fmaxf(fmaxf(sc[3], sc[4]), sc[5]);
            const float m3 = fmaxf(fmaxf(sc[6], sc[7]), sc[8]);
            const float mv = fmaxf(fmaxf(fmaxf(m1, m2), m3), sc[9]);
            const float fvnew = mv + fq[q];
            fvh64[(size_t)r * 64 + lane] = fvnew;      // unmasked, coalesced
            const int rn = r + 8;
            if (rn < L_TOT) fq[q] = feats[(size_t)rn * NTAG + flane];
            #pragma unroll
            for (int f = 0; f < NTAG; ++f)
                fv[f] = __uint_as_float(__builtin_amdgcn_readlane(__float_as_uint(fvnew), f));
        }
    }

    if (lane == 0) {
        float bm = fv[0] + trans[EOS_I * NTAG + 0];
        int ba = 0;
        #pragma unroll
        for (int f = 1; f < NTAG; ++f) {
            const float tv = fv[f] + trans[EOS_I * NTAG + f];
            if (tv > bm) { bm = tv; ba = f; }   // strict > => first-max tie rule
        }
        score_out[0] = bm;
        best_out[0] = ba;
    }
}

// Backpointers, fully parallel, packed 4 steps/dword (reads stride-64 fvh)
__global__ __launch_bounds__(256) void viterbi_bp(const float* __restrict__ fvh64,
                                                  const float* __restrict__ trans,
                                                  unsigned int* __restrict__ bp4) {
    const int idx = blockIdx.x * blockDim.x + threadIdx.x;
    if (idx >= (L_TOT / 4) * NTAG) return;
    const int quad = idx / NTAG, to = idx - quad * NTAG;
    float trow[NTAG];
    #pragma unroll
    for (int f = 0; f < NTAG; ++f) trow[f] = trans[to * NTAG + f];
    unsigned pk = 0;
    #pragma unroll
    for (int q = 0; q < 4; ++q) {
        const int r = quad * 4 + q;
        float best = 0.f;
        int arg = 0;
        #pragma unroll
        for (int f = 0; f < NTAG; ++f) {
            const float fp = r ? fvh64[(size_t)(r - 1) * 64 + f]
                               : ((f == SOS_I) ? 0.f : NEGV);
            const float s = fp + trow[f];
            if (f == 0) best = s;
            else if (s > best) { best = s; arg = f; }  // strict > => first-max
        }
        pk |= (unsigned)arg << (q * 8);
    }
    bp4[(size_t)quad * NTAG + to] = pk;
}

// Chunked backtrace (exact function-composition scan over [10]->[10] maps).
__device__ __forceinline__ int bp_at(const unsigned int* bp4, int t, int tag) {
    return (int)((bp4[(size_t)(t >> 2) * NTAG + tag] >> ((t & 3) * 8)) & 0xffu);
}

__global__ __launch_bounds__(1024) void backtrace(const unsigned int* __restrict__ bp4,
                                                  const int* __restrict__ best_in,
                                                  float* __restrict__ path_out) {
    __shared__ unsigned char fc[128 * NTAG];
    __shared__ unsigned char topt[128];
    const int tid = threadIdx.x;
    for (int pe = tid; pe < 128 * NTAG; pe += 1024) {
        const int c = pe / NTAG, e = pe - c * NTAG;
        int cur = e;
        for (int i = 63; i >= 0; --i) cur = bp_at(bp4, c * 64 + i, cur);
        fc[c * NTAG + e] = (unsigned char)cur;
    }
    __syncthreads();
    if (tid == 0) {
        int carry = best_in[0];
        for (int c = 127; c >= 0; --c) {
            topt[c] = (unsigned char)carry;
            carry = fc[c * NTAG + carry];
        }
    }
    __syncthreads();
    for (int c = tid; c < 128; c += 1024) {
        int cur = topt[c];
        for (int i = 63; i >= 0; --i) {
            const int t = c * 64 + i;
            path_out[t] = (float)cur;
            cur = bp_at(bp4, t, cur);
        }
    }
}

// ---------------------------------------------------------------------------
extern "C" void kernel_launch(void* const* d_in, const int* in_sizes, int n_in,
                              void* d_out, int out_size, void* d_ws, size_t ws_size,
                              hipStream_t stream) {
    const int*   x     = (const int*)d_in[0];
    const float* emb   = (const float*)d_in[3];
    const float* Wih_f = (const float*)d_in[4];
    const float* Whh_f = (const float*)d_in[5];
    const float* bih_f = (const float*)d_in[6];
    const float* bhh_f = (const float*)d_in[7];
    const float* Wih_b = (const float*)d_in[8];
    const float* Whh_b = (const float*)d_in[9];
    const float* bih_b = (const float*)d_in[10];
    const float* bhh_b = (const float*)d_in[11];
    const float* Wout  = (const float*)d_in[12];
    const float* bout  = (const float*)d_in[13];
    const float* trans = (const float*)d_in[14];

    char* ws = (char*)d_ws;
    size_t off = 0;
    auto alloc = [&](size_t bytes) { void* p = ws + off; off += (bytes + 255) & ~(size_t)255; return p; };
    const size_t MB_BYTES = (size_t)16 * 2 * 4 * 256 * 8;                 // 256 KB
    unsigned long long* mb = (unsigned long long*)alloc(MB_BYTES);
    int*           best  = (int*)alloc(256);
    float*         E     = (float*)alloc((size_t)L_TOT * EMBD * 4);       // 8.4 MB
    float*         Wt    = (float*)alloc((size_t)2 * 512 * 1024 * 4);     // 4 MB
    float*         bc    = (float*)alloc(2048 * 4);
    float*         hh    = (float*)alloc((size_t)2 * S_LEN * BB * HID * 4); // 16.8 MB
    float*         fvh64 = (float*)alloc((size_t)L_TOT * 64 * 4);         // 2 MB
    unsigned*      bp4   = (unsigned*)alloc((size_t)(L_TOT / 4) * NTAG * 4); // 80 KB

    float* out   = (float*)d_out;                  // [0 .. 81920)
    float* score = out + (size_t)L_TOT * NTAG;     // [81920]
    float* path  = score + 1;                      // [81921 .. 90113)

    (void)hipMemsetAsync(mb, 0, MB_BYTES, stream);  // kill cross-replay stale tags
    hipLaunchKernelGGL(prep_all,  dim3(12289), dim3(256), 0, stream,
                       x, emb, Wih_f, Whh_f, Wih_b, Whh_b,
                       bih_f, bhh_f, bih_b, bhh_b, E, Wt, bc);
    hipLaunchKernelGGL(lstm_rec,  dim3(256),   dim3(1024), 0, stream, E, Wt, bc, hh, mb);
    hipLaunchKernelGGL(out_proj,  dim3(L_TOT / 128), dim3(128), 0, stream, hh, Wout, bout, out);
    hipLaunchKernelGGL(viterbi_fv, dim3(1),    dim3(64),   0, stream, out, trans, fvh64, score, best);
    hipLaunchKernelGGL(viterbi_bp, dim3(((L_TOT / 4) * NTAG + 255) / 256), dim3(256), 0, stream,
                       fvh64, trans, bp4);
    hipLaunchKernelGGL(backtrace, dim3(1),     dim3(1024), 0, stream, bp4, best, path);
}